// Round 1
// baseline (131.312 us; speedup 1.0000x reference)
//
#include <hip/hip_runtime.h>

#define K_DIM 8192
#define M_OUT 1024
#define N_OUT 4096

typedef __attribute__((ext_vector_type(4))) float f32x4;
typedef __attribute__((ext_vector_type(8))) __bf16 bf16x8;
typedef __attribute__((ext_vector_type(8))) unsigned short u16x8;

__device__ __forceinline__ unsigned short f2bf(float x) {
  unsigned u = __builtin_bit_cast(unsigned, x);
  u += 0x7fffu + ((u >> 16) & 1u);   // round-to-nearest-even
  return (unsigned short)(u >> 16);
}

// ---------------------------------------------------------------------------
// Pass 1: At[j][k] = bf16(D[k] * M[k][j])   (transpose + sign, 64x64 tiles)
// ---------------------------------------------------------------------------
__global__ __launch_bounds__(256) void sign_transpose_kernel(
    const float* __restrict__ Mp, const float* __restrict__ Dp,
    unsigned short* __restrict__ At) {
  __shared__ float tile[64][65];
  const int j0 = blockIdx.x << 6;   // 0..4095
  const int k0 = blockIdx.y << 6;   // 0..8191
  const int t = threadIdx.x;
  {
    const int r = t >> 4;           // 0..15
    const int c4 = (t & 15) << 2;   // 0..60
#pragma unroll
    for (int rr = 0; rr < 4; ++rr) {
      const int k = (rr << 4) + r;
      const float d = Dp[k0 + k];
      const f32x4 v = *(const f32x4*)(Mp + (size_t)(k0 + k) * N_OUT + j0 + c4);
      tile[k][c4 + 0] = v[0] * d;
      tile[k][c4 + 1] = v[1] * d;
      tile[k][c4 + 2] = v[2] * d;
      tile[k][c4 + 3] = v[3] * d;
    }
  }
  __syncthreads();
  {
    const int jin = t >> 3;         // 0..31
    const int k8 = (t & 7) << 3;    // 0..56
#pragma unroll
    for (int half = 0; half < 2; ++half) {
      const int j = jin + (half << 5);
      u16x8 o;
#pragma unroll
      for (int i = 0; i < 8; ++i) o[i] = f2bf(tile[k8 + i][j]);
      *(u16x8*)(At + (size_t)(j0 + j) * K_DIM + k0 + k8) = o;
    }
  }
}

// ---------------------------------------------------------------------------
// Pass 2: Cm[p][k] = bf16( cos(pi*(2P[p]+1)*k/16384) * w[k] ),  w = 1/N (k>0), 0.5/N (k=0)
// exact integer angle reduction: (2P+1)*k mod 32768
// ---------------------------------------------------------------------------
__global__ __launch_bounds__(256) void build_c_kernel(
    const int* __restrict__ Pp, unsigned short* __restrict__ Cm) {
  const int p = blockIdx.x;
  const int n2 = 2 * Pp[p] + 1;
  const int t = threadIdx.x;
#pragma unroll
  for (int ch = 0; ch < 4; ++ch) {
    const int kb = (ch << 11) + (t << 3);
    u16x8 o;
#pragma unroll
    for (int i = 0; i < 8; ++i) {
      const int k = kb + i;
      const unsigned tt = ((unsigned)(n2 * k)) & 32767u;
      const float cv = cosf((float)tt * 1.9174759848570515e-4f);  // pi/16384
      const float wk = (k == 0) ? (0.5f / 8192.0f) : (1.0f / 8192.0f);
      o[i] = f2bf(cv * wk);
    }
    *(u16x8*)(Cm + ((size_t)p << 13) + kb) = o;
  }
}

// ---------------------------------------------------------------------------
// Pass 3: GEMM  part[bz] += Cm[1024x8192] @ At^T  (both operands row-major,
// k-contiguous, 128B rows).  BM=BN=128, BK=64, 256 thr (2x2 waves), dbuf LDS,
// global_load_lds w=16 with pre-swizzled source, XOR swizzle ((row&7)<<4).
// ---------------------------------------------------------------------------
__global__ __launch_bounds__(256, 2) void gemm_kernel(
    const unsigned short* __restrict__ Cm, const unsigned short* __restrict__ At,
    float* __restrict__ outp, int kchunk) {
  __shared__ __align__(16) char lds[2][32768];  // [buf][A:16KB | B:16KB]
  const int bn = blockIdx.x, bm = blockIdx.y, bz = blockIdx.z;
  const int t = threadIdx.x;
  const int w = t >> 6, l = t & 63;
  const int wr = w >> 1, wc = w & 1;
  const int lg = l >> 4, lr = l & 15;
  const int k_begin = bz * kchunk;
  const int k_steps = kchunk >> 6;

  // staging: LDS byte L = i*4096 + t*16 -> row r = i*32 + (t>>3), stored col = (t&7)*16
  // logical col = stored ^ ((r&7)<<4)  (involution; source pre-swizzled)
  const int rbase = t >> 3;
  const int src_c = ((t & 7) << 4) ^ ((rbase & 7) << 4);
  const char* Asrc = (const char*)Cm + ((size_t)(bm * 128 + rbase) << 14) + ((size_t)k_begin << 1) + src_c;
  const char* Bsrc = (const char*)At + ((size_t)(bn * 128 + rbase) << 14) + ((size_t)k_begin << 1) + src_c;

  auto stage = [&](int buf, int kt) {
    const char* a = Asrc + ((size_t)kt << 7);
    const char* b = Bsrc + ((size_t)kt << 7);
    char* la = &lds[buf][0] + (w << 10);      // wave-uniform LDS base
    char* lb = &lds[buf][16384] + (w << 10);
#pragma unroll
    for (int i = 0; i < 4; ++i) {
      __builtin_amdgcn_global_load_lds(
          (const __attribute__((address_space(1))) void*)(a + (size_t)i * (32 << 14)),
          (__attribute__((address_space(3))) void*)(la + (i << 12)), 16, 0, 0);
      __builtin_amdgcn_global_load_lds(
          (const __attribute__((address_space(1))) void*)(b + (size_t)i * (32 << 14)),
          (__attribute__((address_space(3))) void*)(lb + (i << 12)), 16, 0, 0);
    }
  };

  f32x4 acc[4][4] = {};
  const int swz = (lr & 7) << 4;

  stage(0, 0);
  __syncthreads();

  for (int tt = 0; tt < k_steps; ++tt) {
    const int cur = tt & 1;
    if (tt + 1 < k_steps) stage(cur ^ 1, tt + 1);
    const char* base = &lds[cur][0];
    bf16x8 af[2][4], bfr[2][4];
#pragma unroll
    for (int kk = 0; kk < 2; ++kk) {
#pragma unroll
      for (int m = 0; m < 4; ++m)
        af[kk][m] = *(const bf16x8*)(base + ((wr * 64 + m * 16 + lr) << 7) +
                                     (((kk << 6) + (lg << 4)) ^ swz));
#pragma unroll
      for (int n = 0; n < 4; ++n)
        bfr[kk][n] = *(const bf16x8*)(base + 16384 + ((wc * 64 + n * 16 + lr) << 7) +
                                      (((kk << 6) + (lg << 4)) ^ swz));
    }
#pragma unroll
    for (int kk = 0; kk < 2; ++kk)
#pragma unroll
      for (int m = 0; m < 4; ++m)
#pragma unroll
        for (int n = 0; n < 4; ++n)
          acc[m][n] = __builtin_amdgcn_mfma_f32_16x16x32_bf16(af[kk][m], bfr[kk][n], acc[m][n], 0, 0, 0);
    __syncthreads();
  }

  float* po = outp + (size_t)bz * (M_OUT * N_OUT);
  const int orow = bm * 128 + wr * 64 + (lg << 2);
  const int ocol = bn * 128 + wc * 64 + lr;
#pragma unroll
  for (int m = 0; m < 4; ++m)
#pragma unroll
    for (int n = 0; n < 4; ++n)
#pragma unroll
      for (int q = 0; q < 4; ++q)
        po[(size_t)(orow + m * 16 + q) * N_OUT + ocol + n * 16] = acc[m][n][q];
}

// ---------------------------------------------------------------------------
// Pass 4: reduce K-split partials
// ---------------------------------------------------------------------------
__global__ __launch_bounds__(256) void reduce_kernel(
    const float* __restrict__ part, float* __restrict__ out, int ksplit) {
  const size_t total = (size_t)M_OUT * N_OUT;
  const size_t i = ((size_t)blockIdx.x * 256 + threadIdx.x) * 4;
  if (i >= total) return;
  f32x4 s = *(const f32x4*)(part + i);
  for (int s2 = 1; s2 < ksplit; ++s2) s += *(const f32x4*)(part + (size_t)s2 * total + i);
  *(f32x4*)(out + i) = s;
}

// ---------------------------------------------------------------------------
// Fallback (only if workspace is too small): direct f32 evaluation
// ---------------------------------------------------------------------------
__global__ __launch_bounds__(256) void naive_kernel(
    const float* __restrict__ Mp, const float* __restrict__ Dp,
    const int* __restrict__ Pp, float* __restrict__ out) {
  const int p = blockIdx.y;
  const int j = blockIdx.x * 256 + threadIdx.x;
  const int n2 = 2 * Pp[p] + 1;
  float acc = 0.0f;
  for (int k = 0; k < K_DIM; ++k) {
    const unsigned tt = ((unsigned)(n2 * k)) & 32767u;
    const float cv = cosf((float)tt * 1.9174759848570515e-4f);
    const float wk = (k == 0) ? 0.5f : 1.0f;
    acc += cv * wk * Dp[k] * Mp[(size_t)k * N_OUT + j];
  }
  out[(size_t)p * N_OUT + j] = acc * (1.0f / 8192.0f);
}

extern "C" void kernel_launch(void* const* d_in, const int* in_sizes, int n_in,
                              void* d_out, int out_size, void* d_ws, size_t ws_size,
                              hipStream_t stream) {
  const float* Mp = (const float*)d_in[0];
  const float* Dp = (const float*)d_in[1];
  const int* Pp = (const int*)d_in[2];
  float* out = (float*)d_out;

  const size_t AT_BYTES = (size_t)K_DIM * N_OUT * 2;       // 64 MiB
  const size_t CM_BYTES = (size_t)M_OUT * K_DIM * 2;       // 16 MiB
  const size_t PART_BYTES = (size_t)M_OUT * N_OUT * 4;     // 16 MiB per split
  const size_t base_need = AT_BYTES + CM_BYTES;

  int ksplit;
  if (ws_size >= base_need + 4 * PART_BYTES) ksplit = 4;
  else if (ws_size >= base_need + 2 * PART_BYTES) ksplit = 2;
  else if (ws_size >= base_need) ksplit = 1;
  else ksplit = 0;

  if (ksplit == 0) {  // emergency-correctness path
    naive_kernel<<<dim3(N_OUT / 256, M_OUT), 256, 0, stream>>>(Mp, Dp, Pp, out);
    return;
  }

  unsigned short* At = (unsigned short*)d_ws;
  unsigned short* Cm = (unsigned short*)((char*)d_ws + AT_BYTES);
  float* part = (float*)((char*)d_ws + base_need);

  sign_transpose_kernel<<<dim3(N_OUT / 64, K_DIM / 64), 256, 0, stream>>>(Mp, Dp, At);
  build_c_kernel<<<dim3(M_OUT), 256, 0, stream>>>(Pp, Cm);

  float* gout = (ksplit > 1) ? part : out;
  const int kchunk = K_DIM / ksplit;
  gemm_kernel<<<dim3(N_OUT / 128, M_OUT / 128, ksplit), 256, 0, stream>>>(Cm, At, gout, kchunk);

  if (ksplit > 1)
    reduce_kernel<<<dim3((M_OUT * N_OUT / 4 + 255) / 256), 256, 0, stream>>>(part, out, ksplit);
}

// Round 2
// 127.109 us; speedup vs baseline: 1.0331x; 1.0331x over previous
//
#include <hip/hip_runtime.h>

#define K_DIM 8192
#define M_OUT 1024
#define N_OUT 4096

typedef __attribute__((ext_vector_type(4))) float f32x4;
typedef __attribute__((ext_vector_type(8))) __bf16 bf16x8;
typedef __attribute__((ext_vector_type(8))) unsigned short u16x8;

__device__ __forceinline__ unsigned short f2bf(float x) {
  unsigned u = __builtin_bit_cast(unsigned, x);
  u += 0x7fffu + ((u >> 16) & 1u);   // round-to-nearest-even
  return (unsigned short)(u >> 16);
}

// ---------------------------------------------------------------------------
// Pass 1: At[j][k] = bf16(D[k] * M[k][j])   (transpose + sign, 64x64 tiles)
// ---------------------------------------------------------------------------
__global__ __launch_bounds__(256) void sign_transpose_kernel(
    const float* __restrict__ Mp, const float* __restrict__ Dp,
    unsigned short* __restrict__ At) {
  __shared__ float tile[64][65];
  const int j0 = blockIdx.x << 6;
  const int k0 = blockIdx.y << 6;
  const int t = threadIdx.x;
  {
    const int r = t >> 4;
    const int c4 = (t & 15) << 2;
#pragma unroll
    for (int rr = 0; rr < 4; ++rr) {
      const int k = (rr << 4) + r;
      const float d = Dp[k0 + k];
      const f32x4 v = *(const f32x4*)(Mp + (size_t)(k0 + k) * N_OUT + j0 + c4);
      tile[k][c4 + 0] = v[0] * d;
      tile[k][c4 + 1] = v[1] * d;
      tile[k][c4 + 2] = v[2] * d;
      tile[k][c4 + 3] = v[3] * d;
    }
  }
  __syncthreads();
  {
    const int jin = t >> 3;
    const int k8 = (t & 7) << 3;
#pragma unroll
    for (int half = 0; half < 2; ++half) {
      const int j = jin + (half << 5);
      u16x8 o;
#pragma unroll
      for (int i = 0; i < 8; ++i) o[i] = f2bf(tile[k8 + i][j]);
      *(u16x8*)(At + (size_t)(j0 + j) * K_DIM + k0 + k8) = o;
    }
  }
}

// ---------------------------------------------------------------------------
// Pass 2: Cm[p][k] = bf16( cos(pi*(2P[p]+1)*k/16384) * w[k] )
// ---------------------------------------------------------------------------
__global__ __launch_bounds__(256) void build_c_kernel(
    const int* __restrict__ Pp, unsigned short* __restrict__ Cm) {
  const int p = blockIdx.x;
  const int n2 = 2 * Pp[p] + 1;
  const int t = threadIdx.x;
#pragma unroll
  for (int ch = 0; ch < 4; ++ch) {
    const int kb = (ch << 11) + (t << 3);
    u16x8 o;
#pragma unroll
    for (int i = 0; i < 8; ++i) {
      const int k = kb + i;
      const unsigned tt = ((unsigned)(n2 * k)) & 32767u;
      const float cv = cosf((float)tt * 1.9174759848570515e-4f);  // pi/16384
      const float wk = (k == 0) ? (0.5f / 8192.0f) : (1.0f / 8192.0f);
      o[i] = f2bf(cv * wk);
    }
    *(u16x8*)(Cm + ((size_t)p << 13) + kb) = o;
  }
}

// ---------------------------------------------------------------------------
// Pass 3: 256x256 8-phase GEMM (T2 swizzle + T3/T4 counted vmcnt + T5 setprio)
//   part[bz] = Cm[1024x8192] @ At^T, K-split over bz.
//   512 thr = 8 waves (2M x 4N), per-wave 128x64 out, BK=64, LDS 128 KiB.
// ---------------------------------------------------------------------------
template <int MH, int NH>
__device__ __forceinline__ void mmac(f32x4 (&acc)[8][4], const bf16x8 (&Af)[2][4],
                                     const bf16x8 (&Bf)[2][2]) {
  __builtin_amdgcn_s_setprio(1);
#pragma unroll
  for (int kk = 0; kk < 2; ++kk)
#pragma unroll
    for (int m = 0; m < 4; ++m)
#pragma unroll
      for (int n = 0; n < 2; ++n)
        acc[MH * 4 + m][NH * 2 + n] = __builtin_amdgcn_mfma_f32_16x16x32_bf16(
            Af[kk][m], Bf[kk][n], acc[MH * 4 + m][NH * 2 + n], 0, 0, 0);
  __builtin_amdgcn_s_setprio(0);
}

__device__ __forceinline__ void readA(bf16x8 (&Af)[2][4], const char* bufA, int mh,
                                      int x0, int x1) {
#pragma unroll
  for (int m = 0; m < 4; ++m) {
    const char* p = bufA + mh * 8192 + m * 2048;
    Af[0][m] = *(const bf16x8*)(p + x0);
    Af[1][m] = *(const bf16x8*)(p + x1);
  }
}

__device__ __forceinline__ void readB(bf16x8 (&Bf)[2][2], const char* bufB, int nh,
                                      int x0, int x1) {
#pragma unroll
  for (int n = 0; n < 2; ++n) {
    const char* p = bufB + nh * 4096 + n * 2048;
    Bf[0][n] = *(const bf16x8*)(p + x0);
    Bf[1][n] = *(const bf16x8*)(p + x1);
  }
}

__global__ __launch_bounds__(512, 2) void gemm8_kernel(
    const unsigned short* __restrict__ Cm, const unsigned short* __restrict__ At,
    float* __restrict__ outp, int kchunk, int nwg) {
  __shared__ __align__(16) char lds[131072];  // 2 bufs x (A 32K | B 32K)

  // XCD-aware bijective swizzle (nwg % 8 == 0 for all ksplit in {1,2,4})
  const int id = blockIdx.x;
  const int chunk = nwg >> 3;
  const int sid = (id & 7) * chunk + (id >> 3);
  const int bn = sid & 15, bm = (sid >> 4) & 3, bz = sid >> 6;

  const int t = threadIdx.x;
  const int w = t >> 6, l = t & 63;
  const int wr = w >> 2, wc = w & 3;
  const int lg = l >> 4, lr = l & 15;
  const int k_begin = bz * kchunk;
  const int NT = kchunk >> 6;   // K-tiles (64 wide); 32 for ksplit=4
  const int NI = NT >> 1;       // 8-phase iterations (2 tiles each)

  // staging source (pre-swizzled column so LDS stays linear)
  const int trow = t >> 3;                                   // 0..63
  const int tcol = ((t & 7) << 4) ^ ((trow & 7) << 4);       // involution
  const char* Abase = (const char*)Cm + ((size_t)(bm * 256 + trow) << 14) +
                      ((size_t)k_begin << 1) + tcol;
  const char* Bbase = (const char*)At + ((size_t)(bn * 256 + trow) << 14) +
                      ((size_t)k_begin << 1) + tcol;

  auto stage = [&](int buf, int tile, const char* srcbase, int opoff, int h) {
    if (tile >= NT) return;
    char* d = (char*)lds + buf * 65536 + opoff + h * 16384 + t * 16;
    const char* s = srcbase + ((size_t)tile << 7) + ((size_t)h << 21);
#pragma unroll
    for (int i = 0; i < 2; ++i)
      __builtin_amdgcn_global_load_lds(
          (const __attribute__((address_space(1))) void*)(s + ((size_t)i << 20)),
          (__attribute__((address_space(3))) void*)(d + i * 8192), 16, 0, 0);
  };

  // per-thread LDS read bases (XOR bank swizzle on the k-byte within the row)
  const int sw = (lr & 7) << 4;
  const int x0 = (lg << 4) ^ sw;
  const int x1 = (64 + (lg << 4)) ^ sw;
  const char* aP0 = (const char*)lds + wr * 16384 + lr * 128;
  const char* aP1 = aP0 + 65536;
  const char* bP0 = (const char*)lds + 32768 + (wc >> 1) * 16384 + (wc & 1) * 8192 + lr * 128;
  const char* bP1 = bP0 + 65536;

  f32x4 acc[8][4] = {};
  bf16x8 A0f[2][4], A1f[2][4], B0f[2][2], B1f[2][2];

  // prologue: tile0 (A0,A1,B0,B1)->buf0, B0/B1(tile1)->buf1
  stage(0, 0, Abase, 0, 0);
  stage(0, 0, Abase, 0, 1);
  stage(0, 0, Bbase, 32768, 0);
  stage(0, 0, Bbase, 32768, 1);
  stage(1, 1, Bbase, 32768, 0);
  stage(1, 1, Bbase, 32768, 1);
  asm volatile("s_waitcnt vmcnt(4)" ::: "memory");   // tile0 resident
  __builtin_amdgcn_s_barrier();

  for (int it = 0; it < NI; ++it) {
    const int tb = 2 * it;
    const bool lastit = (it == NI - 1);
    // ph1: tile tb q(0,0)
    readA(A0f, aP0, 0, x0, x1);
    readB(B0f, bP0, 0, x0, x1);
    stage(1, tb + 1, Abase, 0, 0);
    __builtin_amdgcn_s_barrier();
    mmac<0, 0>(acc, A0f, B0f);
    __builtin_amdgcn_s_barrier();
    // ph2: q(0,1)
    readB(B1f, bP0, 1, x0, x1);
    stage(1, tb + 1, Abase, 0, 1);
    __builtin_amdgcn_s_barrier();
    mmac<0, 1>(acc, A0f, B1f);
    __builtin_amdgcn_s_barrier();
    // ph3: q(1,0)
    readA(A1f, aP0, 1, x0, x1);
    stage(0, tb + 2, Bbase, 32768, 0);
    __builtin_amdgcn_s_barrier();
    mmac<1, 0>(acc, A1f, B0f);
    __builtin_amdgcn_s_barrier();
    // ph4: q(1,1)  (counted drain: next tile resident, 4 loads stay in flight)
    stage(0, tb + 2, Bbase, 32768, 1);
    __builtin_amdgcn_s_barrier();
    mmac<1, 1>(acc, A1f, B1f);
    if (lastit) { asm volatile("s_waitcnt vmcnt(0)" ::: "memory"); }
    else        { asm volatile("s_waitcnt vmcnt(4)" ::: "memory"); }
    __builtin_amdgcn_s_barrier();
    // ph5: tile tb+1 q(0,0)
    readA(A0f, aP1, 0, x0, x1);
    readB(B0f, bP1, 0, x0, x1);
    stage(0, tb + 2, Abase, 0, 0);
    __builtin_amdgcn_s_barrier();
    mmac<0, 0>(acc, A0f, B0f);
    __builtin_amdgcn_s_barrier();
    // ph6: q(0,1)
    readB(B1f, bP1, 1, x0, x1);
    stage(0, tb + 2, Abase, 0, 1);
    __builtin_amdgcn_s_barrier();
    mmac<0, 1>(acc, A0f, B1f);
    __builtin_amdgcn_s_barrier();
    // ph7: q(1,0)
    readA(A1f, aP1, 1, x0, x1);
    stage(1, tb + 3, Bbase, 32768, 0);
    __builtin_amdgcn_s_barrier();
    mmac<1, 0>(acc, A1f, B0f);
    __builtin_amdgcn_s_barrier();
    // ph8: q(1,1)
    stage(1, tb + 3, Bbase, 32768, 1);
    __builtin_amdgcn_s_barrier();
    mmac<1, 1>(acc, A1f, B1f);
    if (lastit) { asm volatile("s_waitcnt vmcnt(0)" ::: "memory"); }
    else        { asm volatile("s_waitcnt vmcnt(4)" ::: "memory"); }
    __builtin_amdgcn_s_barrier();
  }

  // epilogue
  float* po = outp + (size_t)bz * (M_OUT * N_OUT);
  const int orow = bm * 256 + wr * 128;
  const int ocol = bn * 256 + wc * 64 + lr;
#pragma unroll
  for (int mi = 0; mi < 8; ++mi) {
    const int r0 = orow + (mi >> 2) * 64 + (mi & 3) * 16 + (lg << 2);
#pragma unroll
    for (int ni = 0; ni < 4; ++ni) {
      const int c = ocol + (ni >> 1) * 32 + (ni & 1) * 16;
#pragma unroll
      for (int q = 0; q < 4; ++q)
        po[(size_t)(r0 + q) * N_OUT + c] = acc[mi][ni][q];
    }
  }
}

// ---------------------------------------------------------------------------
// Pass 4: reduce K-split partials
// ---------------------------------------------------------------------------
__global__ __launch_bounds__(256) void reduce_kernel(
    const float* __restrict__ part, float* __restrict__ out, int ksplit) {
  const size_t total = (size_t)M_OUT * N_OUT;
  const size_t i = ((size_t)blockIdx.x * 256 + threadIdx.x) * 4;
  if (i >= total) return;
  f32x4 s = *(const f32x4*)(part + i);
  for (int s2 = 1; s2 < ksplit; ++s2) s += *(const f32x4*)(part + (size_t)s2 * total + i);
  *(f32x4*)(out + i) = s;
}

// ---------------------------------------------------------------------------
// Fallback: direct f32 evaluation
// ---------------------------------------------------------------------------
__global__ __launch_bounds__(256) void naive_kernel(
    const float* __restrict__ Mp, const float* __restrict__ Dp,
    const int* __restrict__ Pp, float* __restrict__ out) {
  const int p = blockIdx.y;
  const int j = blockIdx.x * 256 + threadIdx.x;
  const int n2 = 2 * Pp[p] + 1;
  float acc = 0.0f;
  for (int k = 0; k < K_DIM; ++k) {
    const unsigned tt = ((unsigned)(n2 * k)) & 32767u;
    const float cv = cosf((float)tt * 1.9174759848570515e-4f);
    const float wk = (k == 0) ? 0.5f : 1.0f;
    acc += cv * wk * Dp[k] * Mp[(size_t)k * N_OUT + j];
  }
  out[(size_t)p * N_OUT + j] = acc * (1.0f / 8192.0f);
}

extern "C" void kernel_launch(void* const* d_in, const int* in_sizes, int n_in,
                              void* d_out, int out_size, void* d_ws, size_t ws_size,
                              hipStream_t stream) {
  const float* Mp = (const float*)d_in[0];
  const float* Dp = (const float*)d_in[1];
  const int* Pp = (const int*)d_in[2];
  float* out = (float*)d_out;

  const size_t AT_BYTES = (size_t)K_DIM * N_OUT * 2;       // 64 MiB
  const size_t CM_BYTES = (size_t)M_OUT * K_DIM * 2;       // 16 MiB
  const size_t PART_BYTES = (size_t)M_OUT * N_OUT * 4;     // 16 MiB per split
  const size_t base_need = AT_BYTES + CM_BYTES;

  int ksplit;
  if (ws_size >= base_need + 4 * PART_BYTES) ksplit = 4;
  else if (ws_size >= base_need + 2 * PART_BYTES) ksplit = 2;
  else if (ws_size >= base_need) ksplit = 1;
  else ksplit = 0;

  if (ksplit == 0) {
    naive_kernel<<<dim3(N_OUT / 256, M_OUT), 256, 0, stream>>>(Mp, Dp, Pp, out);
    return;
  }

  unsigned short* At = (unsigned short*)d_ws;
  unsigned short* Cm = (unsigned short*)((char*)d_ws + AT_BYTES);
  float* part = (float*)((char*)d_ws + base_need);

  sign_transpose_kernel<<<dim3(N_OUT / 64, K_DIM / 64), 256, 0, stream>>>(Mp, Dp, At);
  build_c_kernel<<<dim3(M_OUT), 256, 0, stream>>>(Pp, Cm);

  float* gout = (ksplit > 1) ? part : out;
  const int kchunk = K_DIM / ksplit;
  const int nwg = 64 * ksplit;
  gemm8_kernel<<<dim3(nwg), 512, 0, stream>>>(Cm, At, gout, kchunk, nwg);

  if (ksplit > 1)
    reduce_kernel<<<dim3((M_OUT * N_OUT / 4 + 255) / 256), 256, 0, stream>>>(part, out, ksplit);
}

// Round 5
// 109.123 us; speedup vs baseline: 1.2033x; 1.1648x over previous
//
#include <hip/hip_runtime.h>

#define K_DIM 8192
#define M_OUT 1024
#define N_OUT 4096
#define BUFSZ 65536   // per-dbuf LDS: A 32 KiB + B 32 KiB

typedef __attribute__((ext_vector_type(4))) float f32x4;
typedef __attribute__((ext_vector_type(8))) __bf16 bf16x8;
typedef __attribute__((ext_vector_type(2))) __bf16 bf16x2;
typedef __attribute__((ext_vector_type(4))) unsigned u32x4;
typedef __attribute__((ext_vector_type(8))) unsigned short u16x8;

__device__ __forceinline__ unsigned short f2bf(float x) {
  unsigned u = __builtin_bit_cast(unsigned, x);
  u += 0x7fffu + ((u >> 16) & 1u);   // round-to-nearest-even
  return (unsigned short)(u >> 16);
}

__device__ __forceinline__ unsigned pack2(float a, float b) {
  bf16x2 v;
  v[0] = (__bf16)a;   // RNE; compiler lowers pairs to v_cvt_pk_bf16_f32
  v[1] = (__bf16)b;
  return __builtin_bit_cast(unsigned, v);
}

// ---------------------------------------------------------------------------
// Pass 1: Cm[p][k] = bf16( cos(pi*(2P[p]+1)*k/16384) * w[k] * D[k] )
// D = +-1 exact, so folding is lossless.  Exact int angle reduction mod 32768.
// ---------------------------------------------------------------------------
__global__ __launch_bounds__(256) void build_c_kernel(
    const int* __restrict__ Pp, const float* __restrict__ Dp,
    unsigned short* __restrict__ Cm) {
  const int p = blockIdx.x;
  const int n2 = 2 * Pp[p] + 1;
  const int t = threadIdx.x;
#pragma unroll
  for (int ch = 0; ch < 4; ++ch) {
    const int kb = (ch << 11) + (t << 3);
    u16x8 o;
#pragma unroll
    for (int i = 0; i < 8; ++i) {
      const int k = kb + i;
      const unsigned tt = ((unsigned)(n2 * k)) & 32767u;
      const float cv = cosf((float)tt * 1.9174759848570515e-4f);  // pi/16384
      const float wk = (k == 0) ? (0.5f / 8192.0f) : (1.0f / 8192.0f);
      o[i] = f2bf(cv * wk * Dp[k]);
    }
    *(u16x8*)(Cm + ((size_t)p << 13) + kb) = o;
  }
}

// ---------------------------------------------------------------------------
// Pass 2: GEMM  part[bz] = Cm[1024x8192] @ M  (B = M consumed directly, f32)
// BM=BN=256, BK=64, 512 thr (2Mx4N waves).
// A: global_load_lds, source pre-swizzled (verified R2 path).
// B: reg-stage f32x4 -> cvt_pk bf16 -> ds_write_b128 into [n][64k] rows with
//    blk ^= (n&7)^((n>>2)&7) swizzle -> ds_read_b128 fragments (R2 read path).
// ---------------------------------------------------------------------------
__global__ __launch_bounds__(512, 1) void gemm_kernel(
    const unsigned short* __restrict__ Cm, const float* __restrict__ Mp,
    float* __restrict__ outp, int kchunk, int nwg) {
  __shared__ __align__(16) char lds[2 * BUFSZ];

  // XCD-aware bijective swizzle; bm-major so each XCD chunk reuses B panels
  const int id = blockIdx.x;
  const int chunk = nwg >> 3;
  const int sid = (id & 7) * chunk + (id >> 3);
  const int bm = sid & 3, bn = (sid >> 2) & 15, bz = sid >> 6;

  const int t = threadIdx.x;
  const int w = t >> 6, l = t & 63;
  const int wr = w >> 2, wc = w & 3;
  const int lg = l >> 4, lr = l & 15;
  const int k_begin = bz * kchunk;
  const int NT = kchunk >> 6;

  // ---- A staging: global_load_lds, source col pre-swizzled (LDS stays linear)
  const int arow = t >> 3;
  const int acol = ((t & 7) << 4) ^ ((arow & 7) << 4);
  const char* Agl = (const char*)Cm + ((size_t)(bm * 256 + arow) << 14) +
                    ((size_t)k_begin << 1) + acol;
  auto stageA = [&](int nbuf, int tile) {
    char* d = (char*)lds + nbuf * BUFSZ + t * 16;
    const char* s = Agl + ((size_t)tile << 7);
#pragma unroll
    for (int i = 0; i < 4; ++i)
      __builtin_amdgcn_global_load_lds(
          (const __attribute__((address_space(1))) void*)(s + ((size_t)i << 20)),
          (__attribute__((address_space(3))) void*)(d + i * 8192), 16, 0, 0);
  };

  // ---- B staging: thread t handles k = w*8+i (i=0..7), n = (t&63)*4 + nn
  const float* Bg = Mp + (size_t)k_begin * N_OUT + bn * 256 + l * 4;
  auto loadB = [&](f32x4 (&r)[8], int tile, int half) {
#pragma unroll
    for (int i = 0; i < 4; ++i)
      r[half * 4 + i] =
          *(const f32x4*)(Bg + (size_t)(tile * 64 + w * 8 + half * 4 + i) * N_OUT);
  };
  auto writeB = [&](const f32x4 (&r)[8], int nbuf, int nn) {
    const int n = (l << 2) + nn;
    const int sN = (n & 7) ^ ((n >> 2) & 7);
    u32x4 pk;
#pragma unroll
    for (int j = 0; j < 4; ++j) pk[j] = pack2(r[2 * j][nn], r[2 * j + 1][nn]);
    *(u32x4*)(lds + nbuf * BUFSZ + 32768 + n * 128 + ((w ^ sN) << 4)) = pk;
  };

  // ---- fragment read offsets
  const int sw = (lr & 7) << 4;
  const int xk0 = (lg << 4) ^ sw;
  const int xk1 = (64 + (lg << 4)) ^ sw;
  unsigned boff[2][4];
#pragma unroll
  for (int kk = 0; kk < 2; ++kk)
#pragma unroll
    for (int nf = 0; nf < 4; ++nf) {
      const int row = wc * 64 + nf * 16 + lr;
      const int sN = (row & 7) ^ ((row >> 2) & 7);
      boff[kk][nf] = 32768 + row * 128 + ((((kk << 2) | lg) ^ sN) << 4);
    }

  f32x4 acc[8][4] = {};
  bf16x8 Af[4];
  bf16x8 Bf[4];

  auto readA = [&](const char* aBuf, int mh, int xk) {
#pragma unroll
    for (int m = 0; m < 4; ++m)
      Af[m] = *(const bf16x8*)(aBuf + mh * 8192 + m * 2048 + xk);
  };
  auto readB = [&](int nbuf, int kk) {
#pragma unroll
    for (int nf = 0; nf < 4; ++nf)
      Bf[nf] = *(const bf16x8*)(lds + nbuf * BUFSZ + boff[kk][nf]);
  };
  auto mm = [&](int mh) {
    __builtin_amdgcn_s_setprio(1);
#pragma unroll
    for (int m = 0; m < 4; ++m)
#pragma unroll
      for (int nf = 0; nf < 4; ++nf)
        acc[mh * 4 + m][nf] = __builtin_amdgcn_mfma_f32_16x16x32_bf16(
            Af[m], Bf[nf], acc[mh * 4 + m][nf], 0, 0, 0);
    __builtin_amdgcn_s_setprio(0);
  };

#define WAITLGKM() do { asm volatile("s_waitcnt lgkmcnt(0)" ::: "memory"); \
                        __builtin_amdgcn_sched_barrier(0); } while (0)

  // ---- prologue: tile 0 into buf 0
  {
    f32x4 p[8];
    loadB(p, 0, 0);
    loadB(p, 0, 1);
    stageA(0, 0);
#pragma unroll
    for (int nn = 0; nn < 4; ++nn) writeB(p, 0, nn);
    asm volatile("s_waitcnt vmcnt(0) lgkmcnt(0)" ::: "memory");
    __builtin_amdgcn_s_barrier();
    __builtin_amdgcn_sched_barrier(0);
  }

  for (int tt = 0; tt < NT; ++tt) {
    const int cur = tt & 1, nxt = cur ^ 1;
    const char* aBuf = (const char*)lds + cur * BUFSZ + wr * 16384 + lr * 128;
    const bool more = (tt + 1) < NT;
    f32x4 sb[8];
    // sp0: mh0 kk0
    readA(aBuf, 0, xk0);
    readB(cur, 0);
    if (more) loadB(sb, tt + 1, 0);
    WAITLGKM();
    mm(0);
    // sp1: mh0 kk1
    readA(aBuf, 0, xk1);
    readB(cur, 1);
    if (more) { stageA(nxt, tt + 1); loadB(sb, tt + 1, 1); }
    WAITLGKM();
    mm(0);
    // sp2: mh1 kk0
    readA(aBuf, 1, xk0);
    readB(cur, 0);
    WAITLGKM();
    mm(1);
    if (more) { writeB(sb, nxt, 0); writeB(sb, nxt, 1); }
    // sp3: mh1 kk1
    readA(aBuf, 1, xk1);
    readB(cur, 1);
    WAITLGKM();
    mm(1);
    if (more) { writeB(sb, nxt, 2); writeB(sb, nxt, 3); }
    asm volatile("s_waitcnt vmcnt(0) lgkmcnt(0)" ::: "memory");
    __builtin_amdgcn_s_barrier();
    __builtin_amdgcn_sched_barrier(0);
  }
#undef WAITLGKM

  // ---- epilogue
  float* po = outp + (size_t)bz * (M_OUT * N_OUT);
  const int orow = bm * 256 + wr * 128;
  const int ocol = bn * 256 + wc * 64 + lr;
#pragma unroll
  for (int mi = 0; mi < 8; ++mi) {
    const int r0 = orow + (mi >> 2) * 64 + (mi & 3) * 16 + (lg << 2);
#pragma unroll
    for (int ni = 0; ni < 4; ++ni) {
      const int c = ocol + ni * 16;
#pragma unroll
      for (int q = 0; q < 4; ++q)
        po[(size_t)(r0 + q) * N_OUT + c] = acc[mi][ni][q];
    }
  }
}

// ---------------------------------------------------------------------------
// Pass 3: reduce K-split partials
// ---------------------------------------------------------------------------
__global__ __launch_bounds__(256) void reduce_kernel(
    const float* __restrict__ part, float* __restrict__ out, int ksplit) {
  const size_t total = (size_t)M_OUT * N_OUT;
  const size_t i = ((size_t)blockIdx.x * 256 + threadIdx.x) * 4;
  if (i >= total) return;
  f32x4 s = *(const f32x4*)(part + i);
  for (int s2 = 1; s2 < ksplit; ++s2) s += *(const f32x4*)(part + (size_t)s2 * total + i);
  *(f32x4*)(out + i) = s;
}

// ---------------------------------------------------------------------------
// Fallback: direct f32 evaluation
// ---------------------------------------------------------------------------
__global__ __launch_bounds__(256) void naive_kernel(
    const float* __restrict__ Mp, const float* __restrict__ Dp,
    const int* __restrict__ Pp, float* __restrict__ out) {
  const int p = blockIdx.y;
  const int j = blockIdx.x * 256 + threadIdx.x;
  const int n2 = 2 * Pp[p] + 1;
  float acc = 0.0f;
  for (int k = 0; k < K_DIM; ++k) {
    const unsigned tt = ((unsigned)(n2 * k)) & 32767u;
    const float cv = cosf((float)tt * 1.9174759848570515e-4f);
    const float wk = (k == 0) ? 0.5f : 1.0f;
    acc += cv * wk * Dp[k] * Mp[(size_t)k * N_OUT + j];
  }
  out[(size_t)p * N_OUT + j] = acc * (1.0f / 8192.0f);
}

extern "C" void kernel_launch(void* const* d_in, const int* in_sizes, int n_in,
                              void* d_out, int out_size, void* d_ws, size_t ws_size,
                              hipStream_t stream) {
  const float* Mp = (const float*)d_in[0];
  const float* Dp = (const float*)d_in[1];
  const int* Pp = (const int*)d_in[2];
  float* out = (float*)d_out;

  const size_t CM_BYTES = (size_t)M_OUT * K_DIM * 2;       // 16 MiB
  const size_t PART_BYTES = (size_t)M_OUT * N_OUT * 4;     // 16 MiB per split

  int ksplit;
  if (ws_size >= CM_BYTES + 4 * PART_BYTES) ksplit = 4;
  else if (ws_size >= CM_BYTES + 2 * PART_BYTES) ksplit = 2;
  else if (ws_size >= CM_BYTES) ksplit = 1;
  else ksplit = 0;

  if (ksplit == 0) {
    naive_kernel<<<dim3(N_OUT / 256, M_OUT), 256, 0, stream>>>(Mp, Dp, Pp, out);
    return;
  }

  unsigned short* Cm = (unsigned short*)d_ws;
  float* part = (float*)((char*)d_ws + CM_BYTES);

  build_c_kernel<<<dim3(M_OUT), 256, 0, stream>>>(Pp, Dp, Cm);

  float* gout = (ksplit > 1) ? part : out;
  const int kchunk = K_DIM / ksplit;
  const int nwg = 64 * ksplit;
  gemm_kernel<<<dim3(nwg), 512, 0, stream>>>(Cm, Mp, gout, kchunk, nwg);

  if (ksplit > 1)
    reduce_kernel<<<dim3((M_OUT * N_OUT / 4 + 255) / 256), 256, 0, stream>>>(part, out, ksplit);
}

// Round 6
// 108.955 us; speedup vs baseline: 1.2052x; 1.0015x over previous
//
#include <hip/hip_runtime.h>

#define K_DIM 8192
#define M_OUT 1024
#define N_OUT 4096
#define BUFSZ 65536   // per-dbuf LDS: A 32 KiB + B 32 KiB

typedef __attribute__((ext_vector_type(4))) float f32x4;
typedef __attribute__((ext_vector_type(8))) __bf16 bf16x8;
typedef __attribute__((ext_vector_type(2))) __bf16 bf16x2;
typedef __attribute__((ext_vector_type(4))) unsigned u32x4;
typedef __attribute__((ext_vector_type(8))) unsigned short u16x8;

__device__ __forceinline__ unsigned short f2bf(float x) {
  unsigned u = __builtin_bit_cast(unsigned, x);
  u += 0x7fffu + ((u >> 16) & 1u);   // round-to-nearest-even
  return (unsigned short)(u >> 16);
}

__device__ __forceinline__ unsigned pack2(float a, float b) {
  bf16x2 v;
  v[0] = (__bf16)a;   // RNE; compiler lowers pairs to v_cvt_pk_bf16_f32
  v[1] = (__bf16)b;
  return __builtin_bit_cast(unsigned, v);
}

// ---------------------------------------------------------------------------
// Pass 1: Cm[p][k] = bf16( cos(pi*(2P[p]+1)*k/16384) * w[k] * D[k] )
// ---------------------------------------------------------------------------
__global__ __launch_bounds__(256) void build_c_kernel(
    const int* __restrict__ Pp, const float* __restrict__ Dp,
    unsigned short* __restrict__ Cm) {
  const int p = blockIdx.x;
  const int n2 = 2 * Pp[p] + 1;
  const int t = threadIdx.x;
#pragma unroll
  for (int ch = 0; ch < 4; ++ch) {
    const int kb = (ch << 11) + (t << 3);
    u16x8 o;
#pragma unroll
    for (int i = 0; i < 8; ++i) {
      const int k = kb + i;
      const unsigned tt = ((unsigned)(n2 * k)) & 32767u;
      const float cv = cosf((float)tt * 1.9174759848570515e-4f);  // pi/16384
      const float wk = (k == 0) ? (0.5f / 8192.0f) : (1.0f / 8192.0f);
      o[i] = f2bf(cv * wk * Dp[k]);
    }
    *(u16x8*)(Cm + ((size_t)p << 13) + kb) = o;
  }
}

// ---------------------------------------------------------------------------
// Pass 2: GEMM  part[bz] = Cm[1024x8192] @ M  (B = M consumed directly, f32)
// BM=BN=256, BK=64, 512 thr (2Mx4N waves).
// A: global_load_lds, source pre-swizzled.  B: reg-stage f32 -> bf16 ->
// ds_write_b128 swizzled -> ds_read_b128.  One barrier + one full drain per
// K-tile; all intra-tile waits left to the compiler's dep-tracking.
// ---------------------------------------------------------------------------
__global__ __launch_bounds__(512, 1) void gemm_kernel(
    const unsigned short* __restrict__ Cm, const float* __restrict__ Mp,
    float* __restrict__ outp, int kchunk, int nwg) {
  __shared__ __align__(16) char lds[2 * BUFSZ];

  // XCD-aware bijective swizzle; bm-major so each XCD chunk reuses B panels
  const int id = blockIdx.x;
  const int chunk = nwg >> 3;
  const int sid = (id & 7) * chunk + (id >> 3);
  const int bm = sid & 3, bn = (sid >> 2) & 15, bz = sid >> 6;

  const int t = threadIdx.x;
  const int w = t >> 6, l = t & 63;
  const int wr = w >> 2, wc = w & 3;
  const int lg = l >> 4, lr = l & 15;
  const int k_begin = bz * kchunk;
  const int NT = kchunk >> 6;

  // ---- A staging: global_load_lds, source col pre-swizzled (LDS stays linear)
  const int arow = t >> 3;
  const int acol = ((t & 7) << 4) ^ ((arow & 7) << 4);
  const char* Agl = (const char*)Cm + ((size_t)(bm * 256 + arow) << 14) +
                    ((size_t)k_begin << 1) + acol;
  auto stageA = [&](int nbuf, int tile) {
    char* d = (char*)lds + nbuf * BUFSZ + t * 16;
    const char* s = Agl + ((size_t)tile << 7);
#pragma unroll
    for (int i = 0; i < 4; ++i)
      __builtin_amdgcn_global_load_lds(
          (const __attribute__((address_space(1))) void*)(s + ((size_t)i << 20)),
          (__attribute__((address_space(3))) void*)(d + i * 8192), 16, 0, 0);
  };

  // ---- B staging: thread t handles k = w*8+i (i=0..7), n = (t&63)*4 + nn
  const float* Bg = Mp + (size_t)k_begin * N_OUT + bn * 256 + l * 4;
  auto loadB = [&](f32x4 (&r)[8], int tile, int half) {
#pragma unroll
    for (int i = 0; i < 4; ++i)
      r[half * 4 + i] =
          *(const f32x4*)(Bg + (size_t)(tile * 64 + w * 8 + half * 4 + i) * N_OUT);
  };
  auto writeB = [&](const f32x4 (&r)[8], int nbuf, int nn) {
    const int n = (l << 2) + nn;
    const int sN = (n & 7) ^ ((n >> 2) & 7);
    u32x4 pk;
#pragma unroll
    for (int j = 0; j < 4; ++j) pk[j] = pack2(r[2 * j][nn], r[2 * j + 1][nn]);
    *(u32x4*)(lds + nbuf * BUFSZ + 32768 + n * 128 + ((w ^ sN) << 4)) = pk;
  };

  // ---- fragment read offsets
  const int sw = (lr & 7) << 4;
  const int xk0 = (lg << 4) ^ sw;
  const int xk1 = (64 + (lg << 4)) ^ sw;
  unsigned boff[2][4];
#pragma unroll
  for (int kk = 0; kk < 2; ++kk)
#pragma unroll
    for (int nf = 0; nf < 4; ++nf) {
      const int row = wc * 64 + nf * 16 + lr;
      const int sN = (row & 7) ^ ((row >> 2) & 7);
      boff[kk][nf] = 32768 + row * 128 + ((((kk << 2) | lg) ^ sN) << 4);
    }

  f32x4 acc[8][4] = {};
  bf16x8 Af[4];
  bf16x8 Bf[4];

  auto readA = [&](const char* aBuf, int mh, int xk) {
#pragma unroll
    for (int m = 0; m < 4; ++m)
      Af[m] = *(const bf16x8*)(aBuf + mh * 8192 + m * 2048 + xk);
  };
  auto readB = [&](int nbuf, int kk) {
#pragma unroll
    for (int nf = 0; nf < 4; ++nf)
      Bf[nf] = *(const bf16x8*)(lds + nbuf * BUFSZ + boff[kk][nf]);
  };
  auto mm = [&](int mh) {
    __builtin_amdgcn_s_setprio(1);
#pragma unroll
    for (int m = 0; m < 4; ++m)
#pragma unroll
      for (int nf = 0; nf < 4; ++nf)
        acc[mh * 4 + m][nf] = __builtin_amdgcn_mfma_f32_16x16x32_bf16(
            Af[m], Bf[nf], acc[mh * 4 + m][nf], 0, 0, 0);
    __builtin_amdgcn_s_setprio(0);
  };

  // ---- prologue: tile 0 into buf 0
  {
    f32x4 p[8];
    stageA(0, 0);
    loadB(p, 0, 0);
    loadB(p, 0, 1);
#pragma unroll
    for (int nn = 0; nn < 4; ++nn) writeB(p, 0, nn);
    asm volatile("s_waitcnt vmcnt(0) lgkmcnt(0)" ::: "memory");
    __builtin_amdgcn_sched_barrier(0);
    __builtin_amdgcn_s_barrier();
  }

  for (int tt = 0; tt < NT; ++tt) {
    const int cur = tt & 1, nxt = cur ^ 1;
    const char* aBuf = (const char*)lds + cur * BUFSZ + wr * 16384 + lr * 128;
    const bool more = (tt + 1) < NT;
    f32x4 sb[8];
    // issue next tile's loads up front (full-tile latency cover)
    if (more) {
      loadB(sb, tt + 1, 0);
      loadB(sb, tt + 1, 1);
      stageA(nxt, tt + 1);
    }
    // kk0: B frags read once, reused across both mh halves
    readB(cur, 0);
    readA(aBuf, 0, xk0);
    mm(0);
    readA(aBuf, 1, xk0);
    mm(1);
    // mid-tile: write next tile's B (compiler inserts the exact vmcnt for sb)
    if (more) {
      writeB(sb, nxt, 0);
      writeB(sb, nxt, 1);
      writeB(sb, nxt, 2);
      writeB(sb, nxt, 3);
    }
    // kk1
    readB(cur, 1);
    readA(aBuf, 0, xk1);
    mm(0);
    readA(aBuf, 1, xk1);
    mm(1);
    // single drain per tile: stageA(nxt) must be LDS-resident past the barrier
    asm volatile("s_waitcnt vmcnt(0) lgkmcnt(0)" ::: "memory");
    __builtin_amdgcn_sched_barrier(0);
    __builtin_amdgcn_s_barrier();
  }

  // ---- epilogue
  float* po = outp + (size_t)bz * (M_OUT * N_OUT);
  const int orow = bm * 256 + wr * 128;
  const int ocol = bn * 256 + wc * 64 + lr;
#pragma unroll
  for (int mi = 0; mi < 8; ++mi) {
    const int r0 = orow + (mi >> 2) * 64 + (mi & 3) * 16 + (lg << 2);
#pragma unroll
    for (int ni = 0; ni < 4; ++ni) {
      const int c = ocol + ni * 16;
#pragma unroll
      for (int q = 0; q < 4; ++q)
        po[(size_t)(r0 + q) * N_OUT + c] = acc[mi][ni][q];
    }
  }
}

// ---------------------------------------------------------------------------
// Pass 3: reduce K-split partials
// ---------------------------------------------------------------------------
__global__ __launch_bounds__(256) void reduce_kernel(
    const float* __restrict__ part, float* __restrict__ out, int ksplit) {
  const size_t total = (size_t)M_OUT * N_OUT;
  const size_t i = ((size_t)blockIdx.x * 256 + threadIdx.x) * 4;
  if (i >= total) return;
  f32x4 s = *(const f32x4*)(part + i);
  for (int s2 = 1; s2 < ksplit; ++s2) s += *(const f32x4*)(part + (size_t)s2 * total + i);
  *(f32x4*)(out + i) = s;
}

// ---------------------------------------------------------------------------
// Fallback: direct f32 evaluation
// ---------------------------------------------------------------------------
__global__ __launch_bounds__(256) void naive_kernel(
    const float* __restrict__ Mp, const float* __restrict__ Dp,
    const int* __restrict__ Pp, float* __restrict__ out) {
  const int p = blockIdx.y;
  const int j = blockIdx.x * 256 + threadIdx.x;
  const int n2 = 2 * Pp[p] + 1;
  float acc = 0.0f;
  for (int k = 0; k < K_DIM; ++k) {
    const unsigned tt = ((unsigned)(n2 * k)) & 32767u;
    const float cv = cosf((float)tt * 1.9174759848570515e-4f);
    const float wk = (k == 0) ? 0.5f : 1.0f;
    acc += cv * wk * Dp[k] * Mp[(size_t)k * N_OUT + j];
  }
  out[(size_t)p * N_OUT + j] = acc * (1.0f / 8192.0f);
}

extern "C" void kernel_launch(void* const* d_in, const int* in_sizes, int n_in,
                              void* d_out, int out_size, void* d_ws, size_t ws_size,
                              hipStream_t stream) {
  const float* Mp = (const float*)d_in[0];
  const float* Dp = (const float*)d_in[1];
  const int* Pp = (const int*)d_in[2];
  float* out = (float*)d_out;

  const size_t CM_BYTES = (size_t)M_OUT * K_DIM * 2;       // 16 MiB
  const size_t PART_BYTES = (size_t)M_OUT * N_OUT * 4;     // 16 MiB per split

  int ksplit;
  if (ws_size >= CM_BYTES + 4 * PART_BYTES) ksplit = 4;
  else if (ws_size >= CM_BYTES + 2 * PART_BYTES) ksplit = 2;
  else if (ws_size >= CM_BYTES) ksplit = 1;
  else ksplit = 0;

  if (ksplit == 0) {
    naive_kernel<<<dim3(N_OUT / 256, M_OUT), 256, 0, stream>>>(Mp, Dp, Pp, out);
    return;
  }

  unsigned short* Cm = (unsigned short*)d_ws;
  float* part = (float*)((char*)d_ws + CM_BYTES);

  build_c_kernel<<<dim3(M_OUT), 256, 0, stream>>>(Pp, Dp, Cm);

  float* gout = (ksplit > 1) ? part : out;
  const int kchunk = K_DIM / ksplit;
  const int nwg = 64 * ksplit;
  gemm_kernel<<<dim3(nwg), 512, 0, stream>>>(Cm, Mp, gout, kchunk, nwg);

  if (ksplit > 1)
    reduce_kernel<<<dim3((M_OUT * N_OUT / 4 + 255) / 256), 256, 0, stream>>>(part, out, ksplit);
}